// Round 3
// baseline (208.305 us; speedup 1.0000x reference)
//
#include <hip/hip_runtime.h>

#define NA 15
#define GH 34
#define GW 34
#define SP (GH*GW)          // 1156
#define NB (SP*NA)          // 17340
#define MAXC 5000
#define TOPN 300
#define NW64 79             // ceil(MAXC/64)
#define THRESH_OBJ 0.2f
#define NMS_T 0.7f

__constant__ float c_aw[NA] = {45.3f,32.0f,22.6f,90.5f,64.0f,45.3f,181.0f,128.0f,90.5f,271.5f,192.0f,135.8f,362.0f,256.0f,181.0f};
__constant__ float c_ah[NA] = {22.6f,32.0f,45.3f,45.3f,64.0f,90.5f,90.5f,128.0f,181.0f,135.8f,192.0f,271.5f,181.0f,256.0f,362.0f};

// ---------------- decode: anchors + deltas -> clipped proposals, keep mask ----------------
__global__ __launch_bounds__(256) void k_decode(
    const float* __restrict__ cls, const float* __restrict__ pred,
    const int* __restrict__ iminfo, const float* __restrict__ mean,
    const float* __restrict__ stdv, float* __restrict__ boxes,
    float* __restrict__ mscore, int* __restrict__ cnt, int* __restrict__ rank) {
#pragma clang fp contract(off)
  int r = blockIdx.x * 256 + threadIdx.x;
  if (r >= NB) return;
  rank[r] = 0;
  if (r == 0) *cnt = 0;          // counted in k_rank_part (next kernel) — no race
  int n = r % NA;
  int p = r / NA;       // p = h*GW + w
  int w = p % GW;
  int h = p / GW;

  float score = cls[(NA + n) * SP + p];             // channel NA+n, spatial p

  float d0 = pred[(n*4+0)*SP + p] * stdv[0] + mean[0];
  float d1 = pred[(n*4+1)*SP + p] * stdv[1] + mean[1];
  float d2 = pred[(n*4+2)*SP + p] * stdv[2] + mean[2];
  float d3 = pred[(n*4+3)*SP + p] * stdv[3] + mean[3];

  float aw = c_aw[n], ah = c_ah[n];
  float sx = (float)(w * 16);
  float sy = (float)(h * 16);
  float xmin = -0.5f * (aw - 1.0f) + sx;
  float ymin = -0.5f * (ah - 1.0f) + sy;
  float xmax =  0.5f * (aw - 1.0f) + sx;
  float ymax =  0.5f * (ah - 1.0f) + sy;

  float widths  = xmax - xmin + 1.0f;
  float heights = ymax - ymin + 1.0f;
  float ctrx = xmin + 0.5f * (widths - 1.0f);
  float ctry = ymin + 0.5f * (heights - 1.0f);

  float pcx = d0 * widths + ctrx;
  float pcy = d1 * heights + ctry;
  float pw = expf(d2) * widths;
  float ph = expf(d3) * heights;

  float x1 = pcx - 0.5f * (pw - 1.0f);
  float y1 = pcy - 0.5f * (ph - 1.0f);
  float x2 = pcx + 0.5f * (pw - 1.0f);
  float y2 = pcy + 0.5f * (ph - 1.0f);

  float ow = (float)iminfo[1] - 1.0f;
  float oh = (float)iminfo[0] - 1.0f;
  x1 = fminf(fmaxf(x1, 0.0f), ow);
  x2 = fminf(fmaxf(x2, 0.0f), ow);
  y1 = fminf(fmaxf(y1, 0.0f), oh);
  y2 = fminf(fmaxf(y2, 0.0f), oh);

  float ws = x2 - x1 + 1.0f;
  float hs = y2 - y1 + 1.0f;
  bool keep = (score > THRESH_OBJ) && (ws >= 6.0f) && (hs >= 6.0f);

  boxes[r*4+0] = x1;
  boxes[r*4+1] = y1;
  boxes[r*4+2] = x2;
  boxes[r*4+3] = y2;
  mscore[r] = keep ? score : -1.0f;
}

// ---------------- partial rank: grid (i-blocks, j-slices), atomicAdd accumulation ----------------
__global__ __launch_bounds__(256) void k_rank_part(const float* __restrict__ mscore,
    int* __restrict__ rank, int* __restrict__ cnt) {
  constexpr int SLICE = 2176;               // 8 slices * 2176 = 17408 >= 17340
  __shared__ float sm[SLICE];
  int tid = threadIdx.x;
  int i = blockIdx.x * 256 + tid;
  int j0 = blockIdx.y * SLICE;
  for (int j = tid; j < SLICE; j += 256) {
    int jj = j0 + j;
    sm[j] = (jj < NB) ? mscore[jj] : -2.0f;
  }
  __syncthreads();
  float mi = (i < NB) ? mscore[i] : -2.0f;
  bool active = (i < NB) && (mi > THRESH_OBJ);
  if (blockIdx.y == 0 && active) atomicAdd(cnt, 1);
  if (!active) return;
  int r = 0;
  const float4* sm4 = (const float4*)sm;
#pragma unroll 4
  for (int j4 = 0; j4 < SLICE / 4; ++j4) {
    float4 v = sm4[j4];                     // uniform address -> LDS broadcast, conflict-free
    int jb = j0 + j4 * 4;
    r += (v.x > mi || (v.x == mi && jb + 0 < i)) ? 1 : 0;
    r += (v.y > mi || (v.y == mi && jb + 1 < i)) ? 1 : 0;
    r += (v.z > mi || (v.z == mi && jb + 2 < i)) ? 1 : 0;
    r += (v.w > mi || (v.w == mi && jb + 3 < i)) ? 1 : 0;
  }
  atomicAdd(&rank[i], r);
}

// ---------------- scatter boxes into sorted order ----------------
__global__ __launch_bounds__(256) void k_scatter(const float* __restrict__ mscore,
    const int* __restrict__ rank, const float* __restrict__ boxes,
    float* __restrict__ sboxes) {
  int i = blockIdx.x * 256 + threadIdx.x;
  if (i >= NB) return;
  if (mscore[i] <= THRESH_OBJ) return;
  int r = rank[i];
  if (r < MAXC) ((float4*)sboxes)[r] = ((const float4*)boxes)[i];
}

// ---------------- pairwise IoU bitmask (full grid; lower triangle writes zeros) ----------------
__global__ __launch_bounds__(64) void k_iou(const float* __restrict__ sboxes,
    const int* __restrict__ cnt, unsigned long long* __restrict__ mask) {
#pragma clang fp contract(off)
  int N = min(*cnt, MAXC);
  int bi = blockIdx.x, bj = blockIdx.y;
  int t = threadIdx.x;
  int i = bi * 64 + t;
  if (bj < bi) {                      // lower triangle: just zero-fill (ws is poisoned)
    if (i < N) mask[(size_t)i * NW64 + bj] = 0ULL;
    return;
  }
  if (bi * 64 >= N) return;
  __shared__ float4 jb[64];
  int j0 = bj * 64;
  if (j0 + t < N) jb[t] = ((const float4*)sboxes)[j0 + t];
  __syncthreads();
  if (i >= N) return;
  float4 a = ((const float4*)sboxes)[i];
  float areaA = (a.z - a.x + 1.0f) * (a.w - a.y + 1.0f);
  unsigned long long word = 0;
  int jmax = min(64, N - j0);
  for (int jj = 0; jj < jmax; ++jj) {
    int j = j0 + jj;
    if (j <= i) continue;
    float4 b = jb[jj];
    float iw = fminf(a.z, b.z) - fmaxf(a.x, b.x) + 1.0f;
    float ih = fminf(a.w, b.w) - fmaxf(a.y, b.y) + 1.0f;
    iw = fmaxf(iw, 0.0f);
    ih = fmaxf(ih, 0.0f);
    float inter = iw * ih;
    float areaB = (b.z - b.x + 1.0f) * (b.w - b.y + 1.0f);
    float iou = inter / (areaA + areaB - inter);
    if (iou > NMS_T) word |= (1ULL << jj);
  }
  mask[(size_t)i * NW64 + bj] = word;
}

// ---------------- serial greedy NMS: register remv, shfl broadcast, 16-deep prefetch ----------------
__global__ __launch_bounds__(64) void k_nms(const float* __restrict__ sboxes,
    const unsigned long long* __restrict__ mask, const int* __restrict__ cnt,
    float* __restrict__ out) {
  int t = threadIdx.x;
  int N = min(*cnt, MAXC);
  unsigned long long r0 = 0ULL, r1 = 0ULL;   // remv words t and t+64 (t+64 valid for t<15)
  __shared__ int klist[TOPN];
  constexpr int D = 16;                      // 16-deep: ~560 cycles of load-latency cover
  unsigned long long pa[D], pb[D];
#pragma unroll
  for (int d = 0; d < D; ++d) {
    const unsigned long long* row = mask + (size_t)d * NW64;
    bool ok = d < N;
    pa[d] = ok ? row[t] : 0ULL;
    pb[d] = (ok && t + 64 < NW64) ? row[t + 64] : 0ULL;
  }
  int kept = 0;
  for (int i0 = 0; i0 < N; i0 += D) {
    if (kept >= TOPN) break;
#pragma unroll
    for (int d = 0; d < D; ++d) {
      int i = i0 + d;
      if (i < N && kept < TOPN) {
        int w = i >> 6;                      // uniform
        unsigned long long sel = (w < 64) ? r0 : r1;
        unsigned long long wv = __shfl(sel, w & 63, 64);
        if (!((wv >> (i & 63)) & 1ULL)) {
          if (t == 0) klist[kept] = i;
          r0 |= pa[d];
          r1 |= pb[d];
          ++kept;
        }
        int ip = i + D;                      // prefetch D ahead
        const unsigned long long* rowp = mask + (size_t)ip * NW64;
        bool ok = ip < N;
        pa[d] = ok ? rowp[t] : 0ULL;
        pb[d] = (ok && t + 64 < NW64) ? rowp[t + 64] : 0ULL;
      }
    }
  }
  __syncthreads();
  // epilogue: write the FULL 300x5 output (zeros where unfilled) — replaces d_out memset
  for (int e = t; e < TOPN * 5; e += 64) {
    int row = e / 5, col = e % 5;
    float v = 0.0f;
    if (col > 0 && row < kept) v = sboxes[klist[row] * 4 + (col - 1)];
    out[e] = v;
  }
}

extern "C" void kernel_launch(void* const* d_in, const int* in_sizes, int n_in,
                              void* d_out, int out_size, void* d_ws, size_t ws_size,
                              hipStream_t stream) {
  const float* cls  = (const float*)d_in[0];
  const float* pred = (const float*)d_in[1];
  const int*   imi  = (const int*)d_in[2];
  const float* mean = (const float*)d_in[3];
  const float* stdv = (const float*)d_in[4];
  float* out = (float*)d_out;

  char* ws = (char*)d_ws;
  float* boxes  = (float*)(ws);                        // NB*4 floats   = 277440 B
  float* mscore = (float*)(ws + 277440);               // NB floats     = 69360 B
  float* sboxes = (float*)(ws + 346800);               // MAXC*4 floats = 80000 B
  int*   cnt    = (int*)(ws + 426800);                 // 4 B (+pad)
  int*   rank   = (int*)(ws + 426816);                 // NB ints       = 69360 B
  unsigned long long* mask = (unsigned long long*)(ws + 496192); // MAXC*NW64*8 = 3160000 B

  k_decode<<<(NB + 255) / 256, 256, 0, stream>>>(cls, pred, imi, mean, stdv, boxes, mscore, cnt, rank);
  dim3 grank((NB + 255) / 256, 8);
  k_rank_part<<<grank, 256, 0, stream>>>(mscore, rank, cnt);
  k_scatter<<<(NB + 255) / 256, 256, 0, stream>>>(mscore, rank, boxes, sboxes);
  dim3 giou(NW64, NW64);
  k_iou<<<giou, 64, 0, stream>>>(sboxes, cnt, mask);
  k_nms<<<1, 64, 0, stream>>>(sboxes, mask, cnt, out);
}

// Round 4
// 141.576 us; speedup vs baseline: 1.4713x; 1.4713x over previous
//
#include <hip/hip_runtime.h>

#define NA 15
#define GH 34
#define GW 34
#define SP (GH*GW)          // 1156
#define NB (SP*NA)          // 17340
#define MAXC 5000
#define TOPN 300
#define NW 80               // padded words per mask row (79 used + 1 pad)
#define NROWS 5056          // 79 blocks * 64, padded row count
#define THRESH_OBJ 0.2f
#define NMS_T 0.7f

typedef unsigned long long u64;

__constant__ float c_aw[NA] = {45.3f,32.0f,22.6f,90.5f,64.0f,45.3f,181.0f,128.0f,90.5f,271.5f,192.0f,135.8f,362.0f,256.0f,181.0f};
__constant__ float c_ah[NA] = {22.6f,32.0f,45.3f,45.3f,64.0f,90.5f,90.5f,128.0f,181.0f,135.8f,192.0f,271.5f,181.0f,256.0f,362.0f};

// ---------------- decode: anchors + deltas -> clipped proposals, keep mask ----------------
__global__ __launch_bounds__(256) void k_decode(
    const float* __restrict__ cls, const float* __restrict__ pred,
    const int* __restrict__ iminfo, const float* __restrict__ mean,
    const float* __restrict__ stdv, float* __restrict__ boxes,
    float* __restrict__ mscore, int* __restrict__ cnt, int* __restrict__ rank) {
#pragma clang fp contract(off)
  int r = blockIdx.x * 256 + threadIdx.x;
  if (r >= NB) return;
  rank[r] = 0;
  if (r == 0) *cnt = 0;          // counted in k_rank_part (next kernel) — no race
  int n = r % NA;
  int p = r / NA;       // p = h*GW + w
  int w = p % GW;
  int h = p / GW;

  float score = cls[(NA + n) * SP + p];             // channel NA+n, spatial p

  float d0 = pred[(n*4+0)*SP + p] * stdv[0] + mean[0];
  float d1 = pred[(n*4+1)*SP + p] * stdv[1] + mean[1];
  float d2 = pred[(n*4+2)*SP + p] * stdv[2] + mean[2];
  float d3 = pred[(n*4+3)*SP + p] * stdv[3] + mean[3];

  float aw = c_aw[n], ah = c_ah[n];
  float sx = (float)(w * 16);
  float sy = (float)(h * 16);
  float xmin = -0.5f * (aw - 1.0f) + sx;
  float ymin = -0.5f * (ah - 1.0f) + sy;
  float xmax =  0.5f * (aw - 1.0f) + sx;
  float ymax =  0.5f * (ah - 1.0f) + sy;

  float widths  = xmax - xmin + 1.0f;
  float heights = ymax - ymin + 1.0f;
  float ctrx = xmin + 0.5f * (widths - 1.0f);
  float ctry = ymin + 0.5f * (heights - 1.0f);

  float pcx = d0 * widths + ctrx;
  float pcy = d1 * heights + ctry;
  float pw = expf(d2) * widths;
  float ph = expf(d3) * heights;

  float x1 = pcx - 0.5f * (pw - 1.0f);
  float y1 = pcy - 0.5f * (ph - 1.0f);
  float x2 = pcx + 0.5f * (pw - 1.0f);
  float y2 = pcy + 0.5f * (ph - 1.0f);

  float ow = (float)iminfo[1] - 1.0f;
  float oh = (float)iminfo[0] - 1.0f;
  x1 = fminf(fmaxf(x1, 0.0f), ow);
  x2 = fminf(fmaxf(x2, 0.0f), ow);
  y1 = fminf(fmaxf(y1, 0.0f), oh);
  y2 = fminf(fmaxf(y2, 0.0f), oh);

  float ws = x2 - x1 + 1.0f;
  float hs = y2 - y1 + 1.0f;
  bool keep = (score > THRESH_OBJ) && (ws >= 6.0f) && (hs >= 6.0f);

  boxes[r*4+0] = x1;
  boxes[r*4+1] = y1;
  boxes[r*4+2] = x2;
  boxes[r*4+3] = y2;
  mscore[r] = keep ? score : -1.0f;
}

// ---------------- partial rank: grid (i-blocks, 16 j-slices), atomicAdd accumulation ----------------
__global__ __launch_bounds__(256) void k_rank_part(const float* __restrict__ mscore,
    int* __restrict__ rank, int* __restrict__ cnt) {
  constexpr int SLICE = 1088;               // 16 slices * 1088 = 17408 >= 17340
  __shared__ float sm[SLICE];
  int tid = threadIdx.x;
  int i = blockIdx.x * 256 + tid;
  int j0 = blockIdx.y * SLICE;
  for (int j = tid; j < SLICE; j += 256) {
    int jj = j0 + j;
    sm[j] = (jj < NB) ? mscore[jj] : -2.0f;
  }
  __syncthreads();
  float mi = (i < NB) ? mscore[i] : -2.0f;
  bool active = (i < NB) && (mi > THRESH_OBJ);
  if (blockIdx.y == 0 && active) atomicAdd(cnt, 1);
  if (!active) return;
  int r = 0;
  const float4* sm4 = (const float4*)sm;
#pragma unroll 4
  for (int j4 = 0; j4 < SLICE / 4; ++j4) {
    float4 v = sm4[j4];                     // uniform address -> LDS broadcast, conflict-free
    int jb = j0 + j4 * 4;
    r += (v.x > mi || (v.x == mi && jb + 0 < i)) ? 1 : 0;
    r += (v.y > mi || (v.y == mi && jb + 1 < i)) ? 1 : 0;
    r += (v.z > mi || (v.z == mi && jb + 2 < i)) ? 1 : 0;
    r += (v.w > mi || (v.w == mi && jb + 3 < i)) ? 1 : 0;
  }
  atomicAdd(&rank[i], r);
}

// ---------------- scatter boxes into sorted order ----------------
__global__ __launch_bounds__(256) void k_scatter(const float* __restrict__ mscore,
    const int* __restrict__ rank, const float* __restrict__ boxes,
    float* __restrict__ sboxes) {
  int i = blockIdx.x * 256 + threadIdx.x;
  if (i >= NB) return;
  if (mscore[i] <= THRESH_OBJ) return;
  int r = rank[i];
  if (r < MAXC) ((float4*)sboxes)[r] = ((const float4*)boxes)[i];
}

// ---------------- pairwise IoU bitmask, NW=80 layout (all words of rows i<N written) ----------------
__global__ __launch_bounds__(64) void k_iou(const float* __restrict__ sboxes,
    const int* __restrict__ cnt, u64* __restrict__ mask) {
#pragma clang fp contract(off)
  int N = min(*cnt, MAXC);
  int bi = blockIdx.x, bj = blockIdx.y;
  int t = threadIdx.x;
  int i = bi * 64 + t;
  if (bj < bi) {                      // lower triangle: zero-fill (rows must be fully written)
    if (i < N) mask[(size_t)i * NW + bj] = 0ULL;
    return;
  }
  if (bi * 64 >= N) return;
  __shared__ float4 jb[64];
  int j0 = bj * 64;
  if (j0 + t < N) jb[t] = ((const float4*)sboxes)[j0 + t];
  __syncthreads();
  if (i >= N) return;
  float4 a = ((const float4*)sboxes)[i];
  float areaA = (a.z - a.x + 1.0f) * (a.w - a.y + 1.0f);
  u64 word = 0;
  int jmax = min(64, N - j0);         // <=0 for pad word 79 -> writes 0
  for (int jj = 0; jj < jmax; ++jj) {
    int j = j0 + jj;
    if (j <= i) continue;
    float4 b = jb[jj];
    float iw = fminf(a.z, b.z) - fmaxf(a.x, b.x) + 1.0f;
    float ih = fminf(a.w, b.w) - fmaxf(a.y, b.y) + 1.0f;
    iw = fmaxf(iw, 0.0f);
    ih = fmaxf(ih, 0.0f);
    float inter = iw * ih;
    float areaB = (b.z - b.x + 1.0f) * (b.w - b.y + 1.0f);
    float iou = inter / (areaA + areaB - inter);
    if (iou > NMS_T) word |= (1ULL << jj);
  }
  mask[(size_t)i * NW + bj] = word;
}

// ---------------- serial greedy NMS: block-scalar ctz scan, alive-only work ----------------
__device__ __forceinline__ u64 rl64(u64 v, int l) {
  unsigned lo = __builtin_amdgcn_readlane((unsigned)(v & 0xffffffffULL), l);
  unsigned hi = __builtin_amdgcn_readlane((unsigned)(v >> 32), l);
  return ((u64)hi << 32) | (u64)lo;
}

__global__ __launch_bounds__(64) void k_nms(const float* __restrict__ sboxes,
    const u64* __restrict__ mask, const int* __restrict__ cnt,
    float* __restrict__ out) {
  const int t = threadIdx.x;
  const int N = min(*cnt, MAXC);
  const int NBLK = (N + 63) >> 6;
  u64 r0 = 0ULL, r1 = 0ULL;           // remv: lane t owns word t (r0), word 64+t (r1, t<16)
  __shared__ int klist[TOPN];
  int kept = 0;

  u64 colA = 0ULL, colB = 0ULL;       // ping-pong column gathers (lane d = row i0+d, word b)
  if (NBLK > 0) colA = mask[(size_t)t * NW + 0];

  for (int b = 0; b < NBLK; ++b) {
    u64 cc = (b & 1) ? colB : colA;
    if (b + 1 < NBLK) {               // prefetch next block's column
      u64 nx = mask[(size_t)((b + 1) * 64 + t) * NW + (b + 1)];
      if (b & 1) colA = nx; else colB = nx;
    }
    int base = b * 64;
    int nv = N - base; if (nv > 64) nv = 64;
    u64 valid = (nv >= 64) ? ~0ULL : ((1ULL << nv) - 1ULL);
    u64 w = (b < 64) ? rl64(r0, b) : rl64(r1, b - 64);
    u64 avail = ~w & valid;
    u64 kmask = 0ULL;
    while (avail) {                   // executes ONLY for alive candidates (~kept count)
      int d = __builtin_amdgcn_readfirstlane((int)__builtin_ctzll(avail));
      if (t == 0) klist[kept] = base + d;
      ++kept;
      kmask |= (1ULL << d);
      u64 sup = rl64(cc, d);
      avail &= ~(sup | (1ULL << d));
      if (kept >= TOPN) break;
    }
    if (kept >= TOPN) break;          // remaining drain is dead work
    // drain kept rows into r0/r1, chunks of 8 (named regs, one vmcnt wait per chunk)
    while (kmask) {
      u64 km = kmask;
      int n = __popcll(km); if (n > 8) n = 8;
#define NEXTD(dK) int dK = km ? (int)__builtin_ctzll(km) : 0; km &= (km - 1ULL);
      NEXTD(d0) NEXTD(d1) NEXTD(d2) NEXTD(d3) NEXTD(d4) NEXTD(d5) NEXTD(d6) NEXTD(d7)
#undef NEXTD
      kmask = km;
      u64 lo0=0,lo1=0,lo2=0,lo3=0,lo4=0,lo5=0,lo6=0,lo7=0;
      u64 hi0=0,hi1=0,hi2=0,hi3=0,hi4=0,hi5=0,hi6=0,hi7=0;
      int hw = 64 + (t & 15);
#define LOADK(K, dK) if (n > K) { const u64* rp = mask + (size_t)(base + dK) * NW; \
        lo##K = rp[t]; hi##K = rp[hw]; }
      LOADK(0, d0) LOADK(1, d1) LOADK(2, d2) LOADK(3, d3)
      LOADK(4, d4) LOADK(5, d5) LOADK(6, d6) LOADK(7, d7)
#undef LOADK
      r0 |= lo0 | lo1 | lo2 | lo3 | lo4 | lo5 | lo6 | lo7;
      r1 |= hi0 | hi1 | hi2 | hi3 | hi4 | hi5 | hi6 | hi7;
    }
  }
  __syncthreads();
  // epilogue: write the FULL 300x5 output (zeros where unfilled)
  for (int e = t; e < TOPN * 5; e += 64) {
    int row = e / 5, col = e % 5;
    float v = 0.0f;
    if (col > 0 && row < kept) v = sboxes[klist[row] * 4 + (col - 1)];
    out[e] = v;
  }
}

extern "C" void kernel_launch(void* const* d_in, const int* in_sizes, int n_in,
                              void* d_out, int out_size, void* d_ws, size_t ws_size,
                              hipStream_t stream) {
  const float* cls  = (const float*)d_in[0];
  const float* pred = (const float*)d_in[1];
  const int*   imi  = (const int*)d_in[2];
  const float* mean = (const float*)d_in[3];
  const float* stdv = (const float*)d_in[4];
  float* out = (float*)d_out;

  char* ws = (char*)d_ws;
  float* boxes  = (float*)(ws);                        // NB*4 floats   = 277440 B
  float* mscore = (float*)(ws + 277440);               // NB floats     = 69360 B
  float* sboxes = (float*)(ws + 346800);               // MAXC*4 floats = 80000 B
  int*   cnt    = (int*)(ws + 426800);                 // 16 B
  int*   rank   = (int*)(ws + 426816);                 // NB ints       = 69360 B
  u64*   mask   = (u64*)(ws + 496192);                 // NROWS*NW*8    = 3235840 B

  k_decode<<<(NB + 255) / 256, 256, 0, stream>>>(cls, pred, imi, mean, stdv, boxes, mscore, cnt, rank);
  dim3 grank((NB + 255) / 256, 16);
  k_rank_part<<<grank, 256, 0, stream>>>(mscore, rank, cnt);
  k_scatter<<<(NB + 255) / 256, 256, 0, stream>>>(mscore, rank, boxes, sboxes);
  dim3 giou((MAXC + 63) / 64, NW);
  k_iou<<<giou, 64, 0, stream>>>(sboxes, cnt, mask);
  k_nms<<<1, 64, 0, stream>>>(sboxes, mask, cnt, out);
}

// Round 5
// 102.434 us; speedup vs baseline: 2.0336x; 1.3821x over previous
//
#include <hip/hip_runtime.h>

#define NA 15
#define GH 34
#define GW 34
#define SP (GH*GW)          // 1156
#define NB (SP*NA)          // 17340
#define MAXC 5000
#define TOPN 300
#define NW 80               // padded words per mask row (79 used + 1 pad)
#define THRESH_OBJ 0.2f
#define NMS_T 0.7f
// score-bucket constants: positive-float bits are order-preserving
#define SH 12
#define BLO 0x3E4CCu        // bits(0.2f) >> 12
#define NBUCK 5120          // covers bits(1.0)>>12 - BLO = 4916, 5 per scan-thread

typedef unsigned long long u64;
typedef unsigned int u32;

__constant__ float c_aw[NA] = {45.3f,32.0f,22.6f,90.5f,64.0f,45.3f,181.0f,128.0f,90.5f,271.5f,192.0f,135.8f,362.0f,256.0f,181.0f};
__constant__ float c_ah[NA] = {22.6f,32.0f,45.3f,45.3f,64.0f,90.5f,90.5f,128.0f,181.0f,135.8f,192.0f,271.5f,181.0f,256.0f,362.0f};

// ---------------- decode + histogram (hist pre-zeroed by memsetAsync) ----------------
__global__ __launch_bounds__(256) void k_decode(
    const float* __restrict__ cls, const float* __restrict__ pred,
    const int* __restrict__ iminfo, const float* __restrict__ mean,
    const float* __restrict__ stdv, float* __restrict__ boxes,
    u32* __restrict__ sbits, int* __restrict__ hist) {
#pragma clang fp contract(off)
  int r = blockIdx.x * 256 + threadIdx.x;
  if (r >= NB) return;
  int n = r % NA;
  int p = r / NA;       // p = h*GW + w
  int w = p % GW;
  int h = p / GW;

  float score = cls[(NA + n) * SP + p];             // channel NA+n, spatial p

  float d0 = pred[(n*4+0)*SP + p] * stdv[0] + mean[0];
  float d1 = pred[(n*4+1)*SP + p] * stdv[1] + mean[1];
  float d2 = pred[(n*4+2)*SP + p] * stdv[2] + mean[2];
  float d3 = pred[(n*4+3)*SP + p] * stdv[3] + mean[3];

  float aw = c_aw[n], ah = c_ah[n];
  float sx = (float)(w * 16);
  float sy = (float)(h * 16);
  float xmin = -0.5f * (aw - 1.0f) + sx;
  float ymin = -0.5f * (ah - 1.0f) + sy;
  float xmax =  0.5f * (aw - 1.0f) + sx;
  float ymax =  0.5f * (ah - 1.0f) + sy;

  float widths  = xmax - xmin + 1.0f;
  float heights = ymax - ymin + 1.0f;
  float ctrx = xmin + 0.5f * (widths - 1.0f);
  float ctry = ymin + 0.5f * (heights - 1.0f);

  float pcx = d0 * widths + ctrx;
  float pcy = d1 * heights + ctry;
  float pw = expf(d2) * widths;
  float ph = expf(d3) * heights;

  float x1 = pcx - 0.5f * (pw - 1.0f);
  float y1 = pcy - 0.5f * (ph - 1.0f);
  float x2 = pcx + 0.5f * (pw - 1.0f);
  float y2 = pcy + 0.5f * (ph - 1.0f);

  float ow = (float)iminfo[1] - 1.0f;
  float oh = (float)iminfo[0] - 1.0f;
  x1 = fminf(fmaxf(x1, 0.0f), ow);
  x2 = fminf(fmaxf(x2, 0.0f), ow);
  y1 = fminf(fmaxf(y1, 0.0f), oh);
  y2 = fminf(fmaxf(y2, 0.0f), oh);

  float ws = x2 - x1 + 1.0f;
  float hs = y2 - y1 + 1.0f;
  bool keep = (score > THRESH_OBJ) && (ws >= 6.0f) && (hs >= 6.0f);

  boxes[r*4+0] = x1;
  boxes[r*4+1] = y1;
  boxes[r*4+2] = x2;
  boxes[r*4+3] = y2;

  u32 bits = keep ? __float_as_uint(score) : 0u;
  sbits[r] = bits;
  if (bits) {
    int b = min((int)((bits >> SH) - BLO), NBUCK - 1);
    atomicAdd(&hist[b], 1);
  }
}

// ---------------- suffix-scan of bucket histogram: base[b] = #elems in buckets > b ----------------
__global__ __launch_bounds__(1024) void k_scan(const int* __restrict__ hist,
    int* __restrict__ base, int* __restrict__ cnt) {
  __shared__ int sh[NBUCK];
  __shared__ int ch[1024];
  int tid = threadIdx.x;
  for (int j = tid; j < NBUCK; j += 1024) sh[j] = hist[j];
  __syncthreads();
  int c0 = sh[tid*5+0], c1 = sh[tid*5+1], c2 = sh[tid*5+2], c3 = sh[tid*5+3], c4 = sh[tid*5+4];
  ch[tid] = c0 + c1 + c2 + c3 + c4;
  __syncthreads();
  // Hillis-Steele inclusive suffix scan over chunk sums
  for (int off = 1; off < 1024; off <<= 1) {
    int v = ch[tid];
    int u = (tid + off < 1024) ? ch[tid + off] : 0;
    __syncthreads();
    ch[tid] = v + u;
    __syncthreads();
  }
  int S = (tid + 1 < 1024) ? ch[tid + 1] : 0;   // exclusive suffix of chunks after tid
  int b4 = S;
  int b3 = b4 + c4;
  int b2 = b3 + c3;
  int b1 = b2 + c2;
  int b0 = b1 + c1;
  base[tid*5+0] = b0; base[tid*5+1] = b1; base[tid*5+2] = b2;
  base[tid*5+3] = b3; base[tid*5+4] = b4;
  if (tid == 0) *cnt = ch[0];                   // total active
}

// ---------------- place keys into bucket slots (order within bucket irrelevant) ----------------
__global__ __launch_bounds__(256) void k_place(const u32* __restrict__ sbits,
    const int* __restrict__ base, int* __restrict__ fill, u64* __restrict__ blist) {
  int i = blockIdx.x * 256 + threadIdx.x;
  if (i >= NB) return;
  u32 bits = sbits[i];
  if (!bits) return;
  int b = min((int)((bits >> SH) - BLO), NBUCK - 1);
  int pos = base[b] + atomicAdd(&fill[b], 1);
  blist[pos] = ((u64)bits << 32) | (u64)(0xFFFFFFFFu - (u32)i);
}

// ---------------- exact rank = base[b] + within-bucket greater-count; scatter ----------------
__global__ __launch_bounds__(256) void k_final(const u32* __restrict__ sbits,
    const int* __restrict__ hist, const int* __restrict__ base,
    const u64* __restrict__ blist, const float* __restrict__ boxes,
    float* __restrict__ sboxes) {
  int i = blockIdx.x * 256 + threadIdx.x;
  if (i >= NB) return;
  u32 bits = sbits[i];
  if (!bits) return;
  int b = min((int)((bits >> SH) - BLO), NBUCK - 1);
  u64 key = ((u64)bits << 32) | (u64)(0xFFFFFFFFu - (u32)i);
  int s = base[b], n = hist[b];
  int r = s;
  for (int p = s; p < s + n; ++p) r += (blist[p] > key) ? 1 : 0;
  if (r < MAXC) ((float4*)sboxes)[r] = ((const float4*)boxes)[i];
}

// ---------------- pairwise IoU bitmask, NW=80 layout (all words of rows i<N written) ----------------
__global__ __launch_bounds__(64) void k_iou(const float* __restrict__ sboxes,
    const int* __restrict__ cnt, u64* __restrict__ mask) {
#pragma clang fp contract(off)
  int N = min(*cnt, MAXC);
  int bi = blockIdx.x, bj = blockIdx.y;
  int t = threadIdx.x;
  int i = bi * 64 + t;
  if (bj < bi) {                      // lower triangle: zero-fill (rows must be fully written)
    if (i < N) mask[(size_t)i * NW + bj] = 0ULL;
    return;
  }
  if (bi * 64 >= N) return;
  __shared__ float4 jb[64];
  int j0 = bj * 64;
  if (j0 + t < N) jb[t] = ((const float4*)sboxes)[j0 + t];
  __syncthreads();
  if (i >= N) return;
  float4 a = ((const float4*)sboxes)[i];
  float areaA = (a.z - a.x + 1.0f) * (a.w - a.y + 1.0f);
  u64 word = 0;
  int jmax = min(64, N - j0);         // <=0 for pad word 79 -> writes 0
  for (int jj = 0; jj < jmax; ++jj) {
    int j = j0 + jj;
    if (j <= i) continue;
    float4 b = jb[jj];
    float iw = fminf(a.z, b.z) - fmaxf(a.x, b.x) + 1.0f;
    float ih = fminf(a.w, b.w) - fmaxf(a.y, b.y) + 1.0f;
    iw = fmaxf(iw, 0.0f);
    ih = fmaxf(ih, 0.0f);
    float inter = iw * ih;
    float areaB = (b.z - b.x + 1.0f) * (b.w - b.y + 1.0f);
    float iou = inter / (areaA + areaB - inter);
    if (iou > NMS_T) word |= (1ULL << jj);
  }
  mask[(size_t)i * NW + bj] = word;
}

// ---------------- serial greedy NMS: block-scalar ctz scan, alive-only work ----------------
__device__ __forceinline__ u64 rl64(u64 v, int l) {
  unsigned lo = __builtin_amdgcn_readlane((unsigned)(v & 0xffffffffULL), l);
  unsigned hi = __builtin_amdgcn_readlane((unsigned)(v >> 32), l);
  return ((u64)hi << 32) | (u64)lo;
}

__global__ __launch_bounds__(64) void k_nms(const float* __restrict__ sboxes,
    const u64* __restrict__ mask, const int* __restrict__ cnt,
    float* __restrict__ out) {
  const int t = threadIdx.x;
  const int N = min(*cnt, MAXC);
  const int NBLK = (N + 63) >> 6;
  u64 r0 = 0ULL, r1 = 0ULL;           // remv: lane t owns word t (r0), word 64+t (r1, t<16)
  __shared__ int klist[TOPN];
  int kept = 0;

  u64 colA = 0ULL, colB = 0ULL;       // ping-pong column gathers (lane d = row i0+d, word b)
  if (NBLK > 0) colA = mask[(size_t)t * NW + 0];

  for (int b = 0; b < NBLK; ++b) {
    u64 cc = (b & 1) ? colB : colA;
    if (b + 1 < NBLK) {               // prefetch next block's column
      u64 nx = mask[(size_t)((b + 1) * 64 + t) * NW + (b + 1)];
      if (b & 1) colA = nx; else colB = nx;
    }
    int base = b * 64;
    int nv = N - base; if (nv > 64) nv = 64;
    u64 valid = (nv >= 64) ? ~0ULL : ((1ULL << nv) - 1ULL);
    u64 w = (b < 64) ? rl64(r0, b) : rl64(r1, b - 64);
    u64 avail = ~w & valid;
    u64 kmask = 0ULL;
    while (avail) {                   // executes ONLY for alive candidates (~kept count)
      int d = __builtin_amdgcn_readfirstlane((int)__builtin_ctzll(avail));
      if (t == 0) klist[kept] = base + d;
      ++kept;
      kmask |= (1ULL << d);
      u64 sup = rl64(cc, d);
      avail &= ~(sup | (1ULL << d));
      if (kept >= TOPN) break;
    }
    if (kept >= TOPN) break;          // remaining drain is dead work
    // drain kept rows into r0/r1, chunks of 8 (named regs, one vmcnt wait per chunk)
    while (kmask) {
      u64 km = kmask;
      int n = __popcll(km); if (n > 8) n = 8;
#define NEXTD(dK) int dK = km ? (int)__builtin_ctzll(km) : 0; km &= (km - 1ULL);
      NEXTD(d0) NEXTD(d1) NEXTD(d2) NEXTD(d3) NEXTD(d4) NEXTD(d5) NEXTD(d6) NEXTD(d7)
#undef NEXTD
      kmask = km;
      u64 lo0=0,lo1=0,lo2=0,lo3=0,lo4=0,lo5=0,lo6=0,lo7=0;
      u64 hi0=0,hi1=0,hi2=0,hi3=0,hi4=0,hi5=0,hi6=0,hi7=0;
      int hw = 64 + (t & 15);
#define LOADK(K, dK) if (n > K) { const u64* rp = mask + (size_t)(base + dK) * NW; \
        lo##K = rp[t]; hi##K = rp[hw]; }
      LOADK(0, d0) LOADK(1, d1) LOADK(2, d2) LOADK(3, d3)
      LOADK(4, d4) LOADK(5, d5) LOADK(6, d6) LOADK(7, d7)
#undef LOADK
      r0 |= lo0 | lo1 | lo2 | lo3 | lo4 | lo5 | lo6 | lo7;
      r1 |= hi0 | hi1 | hi2 | hi3 | hi4 | hi5 | hi6 | hi7;
    }
  }
  __syncthreads();
  // epilogue: write the FULL 300x5 output (zeros where unfilled)
  for (int e = t; e < TOPN * 5; e += 64) {
    int row = e / 5, col = e % 5;
    float v = 0.0f;
    if (col > 0 && row < kept) v = sboxes[klist[row] * 4 + (col - 1)];
    out[e] = v;
  }
}

extern "C" void kernel_launch(void* const* d_in, const int* in_sizes, int n_in,
                              void* d_out, int out_size, void* d_ws, size_t ws_size,
                              hipStream_t stream) {
  const float* cls  = (const float*)d_in[0];
  const float* pred = (const float*)d_in[1];
  const int*   imi  = (const int*)d_in[2];
  const float* mean = (const float*)d_in[3];
  const float* stdv = (const float*)d_in[4];
  float* out = (float*)d_out;

  char* ws = (char*)d_ws;
  float* boxes  = (float*)(ws);                        // NB*4 floats   = 277440 B
  u32*   sbits  = (u32*)(ws + 277440);                 // NB u32        = 69360 B
  float* sboxes = (float*)(ws + 346800);               // MAXC*4 floats = 80000 B
  int*   cnt    = (int*)(ws + 426800);                 // 16 B
  int*   hist   = (int*)(ws + 426816);                 // NBUCK ints    = 20480 B
  int*   fill   = (int*)(ws + 447296);                 // NBUCK ints    = 20480 B
  int*   base   = (int*)(ws + 467776);                 // NBUCK ints    = 20480 B
  u64*   mask   = (u64*)(ws + 488256);                 // 5056*NW*8     = 3235840 B
  u64*   blist  = mask;   // alias: blist (139264 B) is dead before k_iou writes mask

  hipMemsetAsync(hist, 0, 2 * NBUCK * sizeof(int), stream);   // hist + fill (contiguous)

  k_decode<<<(NB + 255) / 256, 256, 0, stream>>>(cls, pred, imi, mean, stdv, boxes, sbits, hist);
  k_scan<<<1, 1024, 0, stream>>>(hist, base, cnt);
  k_place<<<(NB + 255) / 256, 256, 0, stream>>>(sbits, base, fill, blist);
  k_final<<<(NB + 255) / 256, 256, 0, stream>>>(sbits, hist, base, blist, boxes, sboxes);
  dim3 giou((MAXC + 63) / 64, NW);
  k_iou<<<giou, 64, 0, stream>>>(sboxes, cnt, mask);
  k_nms<<<1, 64, 0, stream>>>(sboxes, mask, cnt, out);
}